// Round 5
// baseline (594.977 us; speedup 1.0000x reference)
//
#include <hip/hip_runtime.h>

typedef float f32x4 __attribute__((ext_vector_type(4)));
typedef float f32x16 __attribute__((ext_vector_type(16)));
typedef short s16x8 __attribute__((ext_vector_type(8)));

#define NT 32768      // tokens
#define NK 8192       // embeddings
#define ND 256        // dim
#define NSP 32        // column splits (NK/256)
#define NKT 12        // K-tiles: logical K=768, BK=64

// round-to-nearest-even fp32 -> bf16 bits
static __device__ __forceinline__ ushort f2bf(float f) {
  unsigned u = __float_as_uint(f);
  unsigned r = (u + 0x7FFFu + ((u >> 16) & 1u)) >> 16;
  return (ushort)r;
}

// ---------------- fp32 [rows][256] -> bf16 split [rows][512] = [hi(256) | lo(256)] ----
__global__ __launch_bounds__(256) void vq_cvt(const float* __restrict__ src,
                                              ushort* __restrict__ dst) {
  size_t idx = (size_t)blockIdx.x * 256 + threadIdx.x;
  size_t n = idx >> 6;
  int dq = (int)(idx & 63) * 4;
  float4 v = *reinterpret_cast<const float4*>(src + n * ND + dq);
  float f[4] = {v.x, v.y, v.z, v.w};
  ushort h[4], l[4];
#pragma unroll
  for (int t = 0; t < 4; ++t) {
    h[t] = f2bf(f[t]);
    float hf = __uint_as_float((unsigned)h[t] << 16);
    l[t] = f2bf(f[t] - hf);   // exact residual, then RN
  }
  *reinterpret_cast<ushort4*>(dst + n * 512 + dq) = make_ushort4(h[0], h[1], h[2], h[3]);
  *reinterpret_cast<ushort4*>(dst + n * 512 + 256 + dq) = make_ushort4(l[0], l[1], l[2], l[3]);
}

// ---------------- ||e_k||^2 (exact fp32) ----------------
__global__ __launch_bounds__(256) void vq_esq(const float* __restrict__ emb,
                                              float* __restrict__ esq) {
  int w = threadIdx.x >> 6, lane = threadIdx.x & 63;
  int k = blockIdx.x * 4 + w;
  const float4 e = *reinterpret_cast<const float4*>(emb + (size_t)k * ND + lane * 4);
  float s = e.x * e.x + e.y * e.y + e.z * e.z + e.w * e.w;
#pragma unroll
  for (int off = 32; off >= 1; off >>= 1) s += __shfl_down(s, off);
  if (lane == 0) esq[k] = s;
}

#define GL16(gp, lp)                                                              \
  __builtin_amdgcn_global_load_lds(                                               \
      (const __attribute__((address_space(1))) unsigned int*)(gp),                \
      (__attribute__((address_space(3))) unsigned int*)(lp), 16, 0, 0)

#define BAR()                                                                     \
  do {                                                                            \
    asm volatile("" ::: "memory");                                                \
    __builtin_amdgcn_s_barrier();                                                 \
    asm volatile("" ::: "memory");                                                \
  } while (0)

// K-tile -> element offset in the [hi(256)|lo(256)] layout.
// terms: 0: z_hi.e_hi (kt 0-3), 1: z_hi.e_lo (kt 4-7), 2: z_lo.e_hi (kt 8-11)
__device__ __forceinline__ int koffA(int kt) { return ((kt >= 8) ? 256 : 0) + (kt & 3) * 64; }
__device__ __forceinline__ int koffB(int kt) { return ((kt >= 4 && kt < 8) ? 256 : 0) + (kt & 3) * 64; }

// ---------------- 256x256 tile, 4 waves x (128x128), 32x32x16 MFMA + per-tile argmin --------
// dist(n,k) = esq[k] - 2*cross   (z^2 row-constant, dropped)
__global__ __launch_bounds__(256, 1) void vq_mfma(
    const ushort* __restrict__ z2, const ushort* __restrict__ e2,
    const float* __restrict__ esq, float* __restrict__ pdist,
    int* __restrict__ pidx) {
  // A: [0,64K)  = [buf][khalf][256 rows][4 slots x 16B] bf16, slot-swizzled:
  //   phys slot p of row r holds logical k-slot p ^ ((r>>1)&3)
  // B: [64K,128K) same layout
  __shared__ __align__(16) char smem[131072];
  char* ldsA = smem;
  char* ldsB = smem + 65536;

  // XCD-aware 8x8 supertile swizzle: each XCD owns 8 supertiles (2MB A + 2MB B panels fit 4MiB L2)
  const int gid = blockIdx.x;
  const int x = gid & 7, c = gid >> 3;        // 512 blocks per XCD
  const int S = x * 8 + (c >> 6);             // global supertile 0..63
  const int wi = c & 63;
  const int mt = (S >> 2) * 8 + (wi >> 3);    // 0..127
  const int nt = (S & 3) * 8 + (wi & 7);      // 0..31
  const int m0 = mt * 256, n0 = nt * 256;

  const int tid = threadIdx.x, lane = tid & 63, wid = tid >> 6;
  const int wr = wid >> 1, wc = wid & 1;      // 2 x 2 waves, per-wave 128x128 output
  const int ll = lane & 31, h = lane >> 5;    // 32x32 frag: row/col = ll, k-group = h
  const int pbase = (ll >> 1) & 3;            // slot-swizzle phase for fragment rows

  // staging: thread t covers row (t>>2), phys 16B slot (t&3); fetch the logical
  // slot that belongs there: sslot = (t&3) ^ ((row>>1)&3) = (t&3) ^ ((t>>3)&3)
  const int sslot = (tid & 3) ^ ((tid >> 3) & 3);
  const ushort* aBase = z2 + (size_t)(m0 + (tid >> 2)) * 512 + sslot * 8;
  const ushort* bBase = e2 + (size_t)(n0 + (tid >> 2)) * 512 + sslot * 8;

  // 256 threads cover 64 rows per GL16 line -> 4 lines per 256-row khalf
#define STAGE_A(kt, kh)                                                           \
  do {                                                                            \
    const ushort* _g = aBase + koffA(kt) + (kh) * 32;                             \
    char* _l = ldsA + (((kt) & 1) << 15) + ((kh) << 14) + tid * 16;               \
    GL16(_g, _l);                 GL16(_g + 32768, _l + 4096);                    \
    GL16(_g + 65536, _l + 8192);  GL16(_g + 98304, _l + 12288);                   \
  } while (0)
#define STAGE_B(kt, kh)                                                           \
  do {                                                                            \
    const ushort* _g = bBase + koffB(kt) + (kh) * 32;                             \
    char* _l = ldsB + (((kt) & 1) << 15) + ((kh) << 14) + tid * 16;               \
    GL16(_g, _l);                 GL16(_g + 32768, _l + 4096);                    \
    GL16(_g + 65536, _l + 8192);  GL16(_g + 98304, _l + 12288);                   \
  } while (0)

  // fragment-read row bases (byte): frag row = wr*128 + mi*32 + ll, 64 B/row
  const int arb = (wr * 128 + ll) * 64;
  const int brb = (wc * 128 + ll) * 64;

  f32x16 acc[4][4];
#pragma unroll
  for (int i = 0; i < 4; ++i)
#pragma unroll
    for (int j = 0; j < 4; ++j)
#pragma unroll
      for (int r = 0; r < 16; ++r) acc[i][j][r] = 0.f;

  // prologue: kt0 complete (16 GL16/wave) + kt1 kh0 (8); vmcnt(8) forces kt0, leaves kt1-kh0
  STAGE_A(0, 0); STAGE_B(0, 0); STAGE_A(0, 1); STAGE_B(0, 1);
  STAGE_A(1, 0); STAGE_B(1, 0);
  asm volatile("s_waitcnt vmcnt(8)" ::: "memory");
  BAR();

  // Per kt: 4 phases (one per 32x32x16 k-step). Phase = {8 ds_read_b128} BAR {stage}
  // {lgkm0 + sched_barrier} {16 MFMA, end unfenced so next reads interleave into issue stalls}.
  // Stage ledger (GL16/wave): enter kt with 8 in flight (kt+1 kh0); +4 at ks0/1 (kt+1 kh1),
  // +4 at ks2/3 (kt+2 kh0); boundary vmcnt(8) forces all kt+1 data, leaves kt+2 kh0.
  // Stage-after-BAR guarantees every wave's reads of the overwritten region completed
  // (each wave lgkm0's its reads one phase earlier, before reaching this barrier).
#pragma unroll 2
  for (int kt = 0; kt < NKT; ++kt) {
    const int bufo = (kt & 1) << 15;
    const char* pa = ldsA + bufo + arb;
    const char* pb = ldsB + bufo + brb;
    s16x8 a[4], b[4];

#pragma unroll
    for (int ks = 0; ks < 4; ++ks) {
      const int ko = (ks >> 1) * 16384;
      const int so = (((((ks & 1) << 1) | h) ^ pbase)) << 4;
#pragma unroll
      for (int mi = 0; mi < 4; ++mi) a[mi] = *(const s16x8*)(pa + ko + mi * 2048 + so);
#pragma unroll
      for (int ni = 0; ni < 4; ++ni) b[ni] = *(const s16x8*)(pb + ko + ni * 2048 + so);
      BAR();
      if (ks == 0)      { if (kt + 1 < NKT) STAGE_A(kt + 1, 1); }
      else if (ks == 1) { if (kt + 1 < NKT) STAGE_B(kt + 1, 1); }
      else if (ks == 2) { if (kt + 2 < NKT) STAGE_A(kt + 2, 0); }
      else              { if (kt + 2 < NKT) STAGE_B(kt + 2, 0); }
      asm volatile("s_waitcnt lgkmcnt(0)" ::: "memory");
      __builtin_amdgcn_sched_barrier(0);
#pragma unroll
      for (int mi = 0; mi < 4; ++mi)
#pragma unroll
        for (int ni = 0; ni < 4; ++ni)
          acc[mi][ni] = __builtin_amdgcn_mfma_f32_32x32x16_bf16(a[mi], b[ni], acc[mi][ni], 0, 0, 0);
    }
    if (kt < NKT - 2) {
      asm volatile("s_waitcnt vmcnt(8)" ::: "memory");
    } else {
      asm volatile("s_waitcnt vmcnt(0)" ::: "memory");
    }
    BAR();
  }

  // ---- epilogue: per-row argmin over this block's 256 cols ----
  // C/D layout (32x32, m74/m101): col = ll, row = (reg&3) + 8*(reg>>2) + 4*h
  float eqv[4];
#pragma unroll
  for (int ni = 0; ni < 4; ++ni) eqv[ni] = esq[n0 + wc * 128 + ni * 32 + ll];

  float* rdv = (float*)smem;                              // [256][68] (pad)
  unsigned char* rdc = (unsigned char*)(smem + 69632);    // [256][64]

#pragma unroll
  for (int mi = 0; mi < 4; ++mi)
#pragma unroll
    for (int reg = 0; reg < 16; ++reg) {
      float bv = 3.4e38f; int bc = 0;
#pragma unroll
      for (int ni = 0; ni < 4; ++ni) {
        float dist = fmaf(-2.f, acc[mi][ni][reg], eqv[ni]);
        int cl = wc * 128 + ni * 32 + ll;
        if (dist < bv) { bv = dist; bc = cl; }   // ni ascending -> first-min kept
      }
      int row = wr * 128 + mi * 32 + (reg & 3) + 8 * (reg >> 2) + 4 * h;
      rdv[row * 68 + wc * 32 + ll] = bv;
      rdc[row * 64 + wc * 32 + ll] = (unsigned char)bc;
    }
  BAR();
  {
    const int row = tid;
    const float* pv = rdv + row * 68;
    const unsigned char* pc = rdc + row * 64;
    float bv = 3.4e38f; int bc = 256;
#pragma unroll 8
    for (int s = 0; s < 64; ++s) {
      float v = pv[s]; int cc = pc[s];
      if (v < bv || (v == bv && cc < bc)) { bv = v; bc = cc; }
    }
    int n = m0 + row;
    pdist[(size_t)n * NSP + nt] = bv;
    pidx[(size_t)n * NSP + nt] = n0 + bc;
  }
}

// ---------------- merge partials, gather z_q, loss partials ----------------
__global__ __launch_bounds__(256) void vq_gather(
    const float* __restrict__ z, const float* __restrict__ emb,
    const float* __restrict__ pdist, const int* __restrict__ pidx,
    float* __restrict__ out, float* __restrict__ lpart) {
  int w = threadIdx.x >> 6, lane = threadIdx.x & 63;
  int n = blockIdx.x * 4 + w;
  int p = lane & (NSP - 1);
  float d = pdist[(size_t)n * NSP + p];
  int ii = pidx[(size_t)n * NSP + p];
#pragma unroll
  for (int off = 1; off < NSP; off <<= 1) {
    float od = __shfl_xor(d, off);
    int oi = __shfl_xor(ii, off);
    if (od < d || (od == d && oi < ii)) { d = od; ii = oi; }
  }
  int bi = ii;   // all lanes agree after butterfly (both 32-halves loaded same data)
  float4 q = *reinterpret_cast<const float4*>(emb + (size_t)bi * ND + lane * 4);
  float4 zz = *reinterpret_cast<const float4*>(z + (size_t)n * ND + lane * 4);
  *reinterpret_cast<float4*>(out + (size_t)n * ND + lane * 4) = q;  // z_q_st fwd == z_q
  float dx = zz.x - q.x, dy = zz.y - q.y, dz = zz.z - q.z, dw = zz.w - q.w;
  float s2 = dx * dx + dy * dy + dz * dz + dw * dw;
#pragma unroll
  for (int off = 32; off >= 1; off >>= 1) s2 += __shfl_down(s2, off);
  __shared__ float ls[4];
  if (lane == 0) {
    ls[w] = s2;
    out[(size_t)NT * ND + 1 + n] = (float)bi;  // indices as float
  }
  __syncthreads();
  if (threadIdx.x == 0) lpart[blockIdx.x] = ls[0] + ls[1] + ls[2] + ls[3];
}

// ---------------- deterministic loss finalize ----------------
__global__ __launch_bounds__(256) void vq_finalize(const float* __restrict__ lpart,
                                                   float* __restrict__ out) {
  __shared__ float s[256];
  float acc = 0.f;
  for (int i = threadIdx.x; i < NT / 4; i += 256) acc += lpart[i];
  s[threadIdx.x] = acc;
  __syncthreads();
  for (int st = 128; st >= 1; st >>= 1) {
    if (threadIdx.x < st) s[threadIdx.x] += s[threadIdx.x + st];
    __syncthreads();
  }
  if (threadIdx.x == 0)
    out[(size_t)NT * ND] = 1.25f * s[0] / (float)((size_t)NT * ND);
}

extern "C" void kernel_launch(void* const* d_in, const int* in_sizes, int n_in,
                              void* d_out, int out_size, void* d_ws, size_t ws_size,
                              hipStream_t stream) {
  const float* z = (const float*)d_in[0];    // (NT, ND) fp32
  const float* emb = (const float*)d_in[1];  // (NK, ND) fp32
  float* out = (float*)d_out;                // [z_q (NT*ND)] [loss (1)] [idx (NT)]

  float* esq = (float*)d_ws;                           // NK f32
  ushort* z2 = (ushort*)(esq + NK);                    // NT*512 bf16
  ushort* e2 = z2 + (size_t)NT * 512;                  // NK*512 bf16
  float* pdist = (float*)(e2 + (size_t)NK * 512);      // NT*NSP f32
  int* pidx = (int*)(pdist + (size_t)NT * NSP);        // NT*NSP i32
  float* lpart = (float*)(pidx + (size_t)NT * NSP);    // NT/4 f32

  vq_cvt<<<NT / 4, 256, 0, stream>>>(z, z2);
  vq_cvt<<<NK / 4, 256, 0, stream>>>(emb, e2);
  vq_esq<<<NK / 4, 256, 0, stream>>>(emb, esq);
  vq_mfma<<<4096, 256, 0, stream>>>(z2, e2, esq, pdist, pidx);
  vq_gather<<<NT / 4, 256, 0, stream>>>(z, emb, pdist, pidx, out, lpart);
  vq_finalize<<<1, 256, 0, stream>>>(lpart, out);
}